// Round 1
// baseline (1319.389 us; speedup 1.0000x reference)
//
#include <hip/hip_runtime.h>
#include <hip/hip_bf16.h>

#define B_ 4
#define S_ 2048
#define DIN 2048
#define DST 2048
#define DOUT 2048
#define NH 16
#define HH 128
#define M_ (B_ * S_)          // 8192
#define OUT_OFF ((size_t)M_ * DOUT)  // 16777216

typedef __attribute__((ext_vector_type(8))) __bf16 bf16x8;
typedef __attribute__((ext_vector_type(4))) float f32x4;

__device__ __forceinline__ unsigned short f2bf(float f) {
    unsigned int u = __float_as_uint(f);
    unsigned int r = u + 0x7FFFu + ((u >> 16) & 1u);
    return (unsigned short)(r >> 16);
}

__device__ __forceinline__ void gload_lds16(const void* g, void* l) {
    __builtin_amdgcn_global_load_lds(
        (const __attribute__((address_space(1))) void*)g,
        (__attribute__((address_space(3))) void*)l, 16, 0, 0);
}

// ---------------- cast x (fp32 -> bf16), 8 elems/thread ----------------
__global__ __launch_bounds__(256) void k_cast_bf16(
    const float* __restrict__ in, unsigned short* __restrict__ out, int n8) {
    int i = blockIdx.x * 256 + threadIdx.x;
    if (i >= n8) return;
    const float4* p = ((const float4*)in) + (size_t)i * 2;
    float4 a = p[0], b = p[1];
    ushort4 r0, r1;
    r0.x = f2bf(a.x); r0.y = f2bf(a.y); r0.z = f2bf(a.z); r0.w = f2bf(a.w);
    r1.x = f2bf(b.x); r1.y = f2bf(b.y); r1.z = f2bf(b.z); r1.w = f2bf(b.w);
    ushort4* o = ((ushort4*)out) + (size_t)i * 2;
    o[0] = r0; o[1] = r1;
}

// ------------- transpose + cast: in[K][N] fp32 -> out[N][K] bf16 -------------
__global__ __launch_bounds__(256) void k_transpose_bf16(
    const float* __restrict__ in, unsigned short* __restrict__ out, int K, int N) {
    __shared__ float tile[64][65];
    int k0 = blockIdx.y * 64, n0 = blockIdx.x * 64;
    int tr  = threadIdx.x >> 4;          // 0..15
    int tc4 = (threadIdx.x & 15) * 4;    // 0..60
#pragma unroll
    for (int p = 0; p < 4; ++p) {
        int r = tr + p * 16;
        float4 v = *(const float4*)&in[(size_t)(k0 + r) * N + n0 + tc4];
        tile[r][tc4 + 0] = v.x; tile[r][tc4 + 1] = v.y;
        tile[r][tc4 + 2] = v.z; tile[r][tc4 + 3] = v.w;
    }
    __syncthreads();
#pragma unroll
    for (int p = 0; p < 4; ++p) {
        int n = tr + p * 16;
        ushort4 o;
        o.x = f2bf(tile[tc4 + 0][n]); o.y = f2bf(tile[tc4 + 1][n]);
        o.z = f2bf(tile[tc4 + 2][n]); o.w = f2bf(tile[tc4 + 3][n]);
        *(ushort4*)&out[(size_t)(n0 + n) * K + k0 + tc4] = o;
    }
}

// ---------------- bf16 GEMM: C[M][N] = A[M][K] * Bt[N][K]^T (+bias) ----------------
// 128x128 tile, BK=64, 4 waves (2x2), 16x16x32 MFMA, global_load_lds w/ XOR swizzle
__global__ __launch_bounds__(256, 2) void k_gemm_bt(
    const unsigned short* __restrict__ A,
    const unsigned short* __restrict__ Bt,
    float* __restrict__ C,
    const float* __restrict__ bias,
    int M, int N, int K, int hasBias) {
    __shared__ unsigned short As[128 * 64];
    __shared__ unsigned short Bs[128 * 64];
    const int tid  = threadIdx.x;
    const int lane = tid & 63;
    const int wid  = tid >> 6;
    const int wr = wid >> 1, wc = wid & 1;
    const int row0 = blockIdx.y * 128, col0 = blockIdx.x * 128;

    f32x4 acc[4][4];
#pragma unroll
    for (int m = 0; m < 4; ++m)
#pragma unroll
        for (int n = 0; n < 4; ++n) acc[m][n] = (f32x4)(0.f);

    const char* Abase = (const char*)(A + (size_t)row0 * K);
    const char* Bbase = (const char*)(Bt + (size_t)col0 * K);

    int srow[4], skb[4];
#pragma unroll
    for (int i = 0; i < 4; ++i) {
        unsigned o = (unsigned)(i * 256 + tid) * 16u;
        unsigned l = o ^ (((o >> 7) & 7u) << 4);   // inverse-swizzled linear index
        srow[i] = (int)(l >> 7);
        skb[i]  = (int)(l & 127u);
    }

    for (int kt = 0; kt < K; kt += 64) {
#pragma unroll
        for (int i = 0; i < 4; ++i) {
            unsigned o = (unsigned)(i * 256 + tid) * 16u;
            gload_lds16(Abase + (size_t)srow[i] * (K * 2) + (size_t)kt * 2 + skb[i],
                        (char*)As + o);
            gload_lds16(Bbase + (size_t)srow[i] * (K * 2) + (size_t)kt * 2 + skb[i],
                        (char*)Bs + o);
        }
        asm volatile("s_waitcnt vmcnt(0)" ::: "memory");
        __syncthreads();
#pragma unroll
        for (int ks = 0; ks < 2; ++ks) {
            bf16x8 af[4], bfr[4];
#pragma unroll
            for (int m = 0; m < 4; ++m) {
                int row = wr * 64 + m * 16 + (lane & 15);
                unsigned o = (unsigned)(row * 128 + ks * 64 + ((lane >> 4) * 16));
                o ^= ((unsigned)(row & 7) << 4);
                af[m] = *(const bf16x8*)((const char*)As + o);
            }
#pragma unroll
            for (int n = 0; n < 4; ++n) {
                int col = wc * 64 + n * 16 + (lane & 15);
                unsigned o = (unsigned)(col * 128 + ks * 64 + ((lane >> 4) * 16));
                o ^= ((unsigned)(col & 7) << 4);
                bfr[n] = *(const bf16x8*)((const char*)Bs + o);
            }
#pragma unroll
            for (int m = 0; m < 4; ++m)
#pragma unroll
                for (int n = 0; n < 4; ++n)
                    acc[m][n] = __builtin_amdgcn_mfma_f32_16x16x32_bf16(
                        af[m], bfr[n], acc[m][n], 0, 0, 0);
        }
        __syncthreads();
    }

#pragma unroll
    for (int n = 0; n < 4; ++n) {
        int gcol = col0 + wc * 64 + n * 16 + (lane & 15);
        float bv = hasBias ? bias[gcol] : 0.f;
#pragma unroll
        for (int m = 0; m < 4; ++m) {
            int growb = row0 + wr * 64 + m * 16 + ((lane >> 4) * 4);
            float* cp = C + (size_t)growb * N + gcol;
#pragma unroll
            for (int r = 0; r < 4; ++r) cp[(size_t)r * N] = acc[m][n][r] + bv;
        }
    }
}

// ---------------- RNN scan: one WG per (batch, head) chain ----------------
// h_{t+1} = tanh(h_t @ W[n] + xp[b,t,n,:]) ; W column-slices in registers.
__global__ __launch_bounds__(256) void k_scan(
    const float* __restrict__ xp,        // [M_][2048] fp32
    const float* __restrict__ h0,        // [B_][2048]
    const float* __restrict__ sw,        // [NH][HH][HH]
    unsigned short* __restrict__ hsb,    // [M_][2048] bf16 out
    float* __restrict__ out_state) {     // [B_][2048] fp32
    __shared__ float hbuf[HH];
    __shared__ float pbuf[8 * HH];
    const int tid = threadIdx.x;
    const int bb = blockIdx.x >> 4;
    const int nn = blockIdx.x & 15;
    const int cg = (tid & 31) * 4;   // 4 output cols
    const int sg = tid >> 5;         // 8 reduction segments of 16

    float w[16][4];
    const float* wb = sw + nn * HH * HH;
#pragma unroll
    for (int i = 0; i < 16; ++i) {
        float4 v = *(const float4*)&wb[(size_t)(sg * 16 + i) * HH + cg];
        w[i][0] = v.x; w[i][1] = v.y; w[i][2] = v.z; w[i][3] = v.w;
    }
    if (tid < HH) hbuf[tid] = h0[bb * DST + nn * HH + tid];
    __syncthreads();

    const float* xrow = xp + (size_t)bb * S_ * DST + nn * HH;
    unsigned short* hrow = hsb + (size_t)bb * S_ * DST + nn * HH;
    float xv = (tid < HH) ? xrow[tid] : 0.f;

    for (int t = 0; t < S_; ++t) {
        float xn = 0.f;
        if (tid < HH && t + 1 < S_) xn = xrow[(size_t)(t + 1) * DST + tid];

        float acc0 = 0.f, acc1 = 0.f, acc2 = 0.f, acc3 = 0.f;
#pragma unroll
        for (int i4 = 0; i4 < 4; ++i4) {
            float4 hv = *(const float4*)&hbuf[sg * 16 + i4 * 4];
            float hh[4] = {hv.x, hv.y, hv.z, hv.w};
#pragma unroll
            for (int j = 0; j < 4; ++j) {
                acc0 = fmaf(hh[j], w[i4 * 4 + j][0], acc0);
                acc1 = fmaf(hh[j], w[i4 * 4 + j][1], acc1);
                acc2 = fmaf(hh[j], w[i4 * 4 + j][2], acc2);
                acc3 = fmaf(hh[j], w[i4 * 4 + j][3], acc3);
            }
        }
        *(float4*)&pbuf[sg * HH + cg] = float4{acc0, acc1, acc2, acc3};
        __syncthreads();
        if (tid < HH) {
            float s = xv;
#pragma unroll
            for (int s8 = 0; s8 < 8; ++s8) s += pbuf[s8 * HH + tid];
            float hn = tanhf(s);
            hbuf[tid] = hn;
            hrow[(size_t)t * DST + tid] = f2bf(hn);
            if (t == S_ - 1) out_state[bb * DST + nn * HH + tid] = hn;
        }
        __syncthreads();
        xv = xn;
    }
}

extern "C" void kernel_launch(void* const* d_in, const int* in_sizes, int n_in,
                              void* d_out, int out_size, void* d_ws, size_t ws_size,
                              hipStream_t stream) {
    const float* x    = (const float*)d_in[0];
    const float* h0   = (const float*)d_in[1];
    const float* Wi   = (const float*)d_in[2];
    const float* bias = (const float*)d_in[3];
    const float* sw   = (const float*)d_in[4];
    const float* Wo   = (const float*)d_in[5];
    float* out = (float*)d_out;

    char* ws = (char*)d_ws;
    unsigned short* xb  = (unsigned short*)ws;                     // 32MB (reused as hs bf16)
    unsigned short* wit = (unsigned short*)(ws + 33554432);        // 8MB
    unsigned short* wot = (unsigned short*)(ws + 41943040);        // 8MB
    float*          xp  = (float*)(ws + 50331648);                 // 64MB

    // 1. cast x -> bf16
    k_cast_bf16<<<8192, 256, 0, stream>>>(x, xb, (M_ * DIN) / 8);
    // 2. transpose+cast weights
    dim3 tg(32, 32);
    k_transpose_bf16<<<tg, 256, 0, stream>>>(Wi, wit, DIN, DST);
    k_transpose_bf16<<<tg, 256, 0, stream>>>(Wo, wot, DST, DOUT);
    // 3. xp = x @ Wi + b   (fp32 out)
    dim3 g1(DST / 128, M_ / 128);
    k_gemm_bt<<<g1, 256, 0, stream>>>(xb, wit, xp, bias, M_, DST, DIN, 1);
    // 4. sequential scan (writes hs bf16 over xb region + final state)
    k_scan<<<B_ * NH, 256, 0, stream>>>(xp, h0, sw, xb, out + OUT_OFF);
    // 5. out = hs @ Wo
    dim3 g2(DOUT / 128, M_ / 128);
    k_gemm_bt<<<g2, 256, 0, stream>>>(xb, wot, out, nullptr, M_, DOUT, DST, 0);
}

// Round 2
// 1165.624 us; speedup vs baseline: 1.1319x; 1.1319x over previous
//
#include <hip/hip_runtime.h>
#include <hip/hip_bf16.h>

#define B_ 4
#define S_ 2048
#define DIN 2048
#define DST 2048
#define DOUT 2048
#define NH 16
#define HH 128
#define M_ (B_ * S_)          // 8192
#define OUT_OFF ((size_t)M_ * DOUT)  // 16777216

typedef __attribute__((ext_vector_type(8))) __bf16 bf16x8;
typedef __attribute__((ext_vector_type(4))) float f32x4;

__device__ __forceinline__ unsigned short f2bf(float f) {
    unsigned int u = __float_as_uint(f);
    unsigned int r = u + 0x7FFFu + ((u >> 16) & 1u);
    return (unsigned short)(r >> 16);
}

__device__ __forceinline__ void gload_lds16(const void* g, void* l) {
    __builtin_amdgcn_global_load_lds(
        (const __attribute__((address_space(1))) void*)g,
        (__attribute__((address_space(3))) void*)l, 16, 0, 0);
}

// ---------------- cast x (fp32 -> bf16), 8 elems/thread ----------------
__global__ __launch_bounds__(256) void k_cast_bf16(
    const float* __restrict__ in, unsigned short* __restrict__ out, int n8) {
    int i = blockIdx.x * 256 + threadIdx.x;
    if (i >= n8) return;
    const float4* p = ((const float4*)in) + (size_t)i * 2;
    float4 a = p[0], b = p[1];
    ushort4 r0, r1;
    r0.x = f2bf(a.x); r0.y = f2bf(a.y); r0.z = f2bf(a.z); r0.w = f2bf(a.w);
    r1.x = f2bf(b.x); r1.y = f2bf(b.y); r1.z = f2bf(b.z); r1.w = f2bf(b.w);
    ushort4* o = ((ushort4*)out) + (size_t)i * 2;
    o[0] = r0; o[1] = r1;
}

// ------------- transpose + cast: in[K][N] fp32 -> out[N][K] bf16 -------------
__global__ __launch_bounds__(256) void k_transpose_bf16(
    const float* __restrict__ in, unsigned short* __restrict__ out, int K, int N) {
    __shared__ float tile[64][65];
    int k0 = blockIdx.y * 64, n0 = blockIdx.x * 64;
    int tr  = threadIdx.x >> 4;          // 0..15
    int tc4 = (threadIdx.x & 15) * 4;    // 0..60
#pragma unroll
    for (int p = 0; p < 4; ++p) {
        int r = tr + p * 16;
        float4 v = *(const float4*)&in[(size_t)(k0 + r) * N + n0 + tc4];
        tile[r][tc4 + 0] = v.x; tile[r][tc4 + 1] = v.y;
        tile[r][tc4 + 2] = v.z; tile[r][tc4 + 3] = v.w;
    }
    __syncthreads();
#pragma unroll
    for (int p = 0; p < 4; ++p) {
        int n = tr + p * 16;
        ushort4 o;
        o.x = f2bf(tile[tc4 + 0][n]); o.y = f2bf(tile[tc4 + 1][n]);
        o.z = f2bf(tile[tc4 + 2][n]); o.w = f2bf(tile[tc4 + 3][n]);
        *(ushort4*)&out[(size_t)(n0 + n) * K + k0 + tc4] = o;
    }
}

// ---------------- bf16 GEMM: C[M][N] = A[M][K] * Bt[N][K]^T (+bias) ----------------
// 128x128 tile, BK=64, 4 waves (2x2), 16x16x32 MFMA, global_load_lds w/ XOR swizzle
__global__ __launch_bounds__(256, 2) void k_gemm_bt(
    const unsigned short* __restrict__ A,
    const unsigned short* __restrict__ Bt,
    float* __restrict__ C,
    const float* __restrict__ bias,
    int M, int N, int K, int hasBias) {
    __shared__ unsigned short As[128 * 64];
    __shared__ unsigned short Bs[128 * 64];
    const int tid  = threadIdx.x;
    const int lane = tid & 63;
    const int wid  = tid >> 6;
    const int wr = wid >> 1, wc = wid & 1;
    const int row0 = blockIdx.y * 128, col0 = blockIdx.x * 128;

    f32x4 acc[4][4];
#pragma unroll
    for (int m = 0; m < 4; ++m)
#pragma unroll
        for (int n = 0; n < 4; ++n) acc[m][n] = (f32x4)(0.f);

    const char* Abase = (const char*)(A + (size_t)row0 * K);
    const char* Bbase = (const char*)(Bt + (size_t)col0 * K);

    int srow[4], skb[4];
#pragma unroll
    for (int i = 0; i < 4; ++i) {
        unsigned o = (unsigned)(i * 256 + tid) * 16u;
        unsigned l = o ^ (((o >> 7) & 7u) << 4);   // inverse-swizzled linear index
        srow[i] = (int)(l >> 7);
        skb[i]  = (int)(l & 127u);
    }

    for (int kt = 0; kt < K; kt += 64) {
#pragma unroll
        for (int i = 0; i < 4; ++i) {
            unsigned o = (unsigned)(i * 256 + tid) * 16u;
            gload_lds16(Abase + (size_t)srow[i] * (K * 2) + (size_t)kt * 2 + skb[i],
                        (char*)As + o);
            gload_lds16(Bbase + (size_t)srow[i] * (K * 2) + (size_t)kt * 2 + skb[i],
                        (char*)Bs + o);
        }
        asm volatile("s_waitcnt vmcnt(0)" ::: "memory");
        __syncthreads();
#pragma unroll
        for (int ks = 0; ks < 2; ++ks) {
            bf16x8 af[4], bfr[4];
#pragma unroll
            for (int m = 0; m < 4; ++m) {
                int row = wr * 64 + m * 16 + (lane & 15);
                unsigned o = (unsigned)(row * 128 + ks * 64 + ((lane >> 4) * 16));
                o ^= ((unsigned)(row & 7) << 4);
                af[m] = *(const bf16x8*)((const char*)As + o);
            }
#pragma unroll
            for (int n = 0; n < 4; ++n) {
                int col = wc * 64 + n * 16 + (lane & 15);
                unsigned o = (unsigned)(col * 128 + ks * 64 + ((lane >> 4) * 16));
                o ^= ((unsigned)(col & 7) << 4);
                bfr[n] = *(const bf16x8*)((const char*)Bs + o);
            }
#pragma unroll
            for (int m = 0; m < 4; ++m)
#pragma unroll
                for (int n = 0; n < 4; ++n)
                    acc[m][n] = __builtin_amdgcn_mfma_f32_16x16x32_bf16(
                        af[m], bfr[n], acc[m][n], 0, 0, 0);
        }
        __syncthreads();
    }

#pragma unroll
    for (int n = 0; n < 4; ++n) {
        int gcol = col0 + wc * 64 + n * 16 + (lane & 15);
        float bv = hasBias ? bias[gcol] : 0.f;
#pragma unroll
        for (int m = 0; m < 4; ++m) {
            int growb = row0 + wr * 64 + m * 16 + ((lane >> 4) * 4);
            float* cp = C + (size_t)growb * N + gcol;
#pragma unroll
            for (int r = 0; r < 4; ++r) cp[(size_t)r * N] = acc[m][n][r] + bv;
        }
    }
}

// ---------------- RNN scan: one WG per (batch, head) chain ----------------
// Lane layout: col = wave*32 + lane/2, row-half = (lane&1)*64.
// W column-half (64 floats) lives in VGPRs; pair-reduce via shfl_xor(1);
// double-buffered h in LDS -> ONE raw s_barrier per step (lgkmcnt only,
// so global hs stores + xp prefetch are never drained at the barrier).
__global__ __launch_bounds__(256, 1) void k_scan(
    const float* __restrict__ xp,        // [M_][2048] fp32
    const float* __restrict__ h0,        // [B_][2048]
    const float* __restrict__ sw,        // [NH][HH][HH]
    unsigned short* __restrict__ hsb,    // [M_][2048] bf16 out
    float* __restrict__ out_state) {     // [B_][2048] fp32
    __shared__ float hb[2][HH];
    const int tid  = threadIdx.x;
    const int lane = tid & 63;
    const int wv   = tid >> 6;
    const int col  = wv * 32 + (lane >> 1);
    const int rh   = (lane & 1) * 64;
    const int bb = blockIdx.x >> 4;
    const int nn = blockIdx.x & 15;

    // W[rh + k][col], k = 0..63 -> registers
    const float* wbp = sw + (size_t)nn * HH * HH + (size_t)rh * HH + col;
    float w[64];
#pragma unroll
    for (int k = 0; k < 64; ++k) w[k] = wbp[(size_t)k * HH];

    if (tid < HH) hb[0][tid] = h0[bb * DST + nn * HH + tid];

    const float* xrow = xp + (size_t)bb * S_ * DST + nn * HH + col;
    unsigned short* hcol = hsb + (size_t)bb * S_ * DST + nn * HH + col;
    float* osp = out_state + bb * DST + nn * HH + col;

    // 2-deep xp prefetch
    float xv  = xrow[0];
    float xn1 = xrow[DST];

    asm volatile("s_waitcnt lgkmcnt(0)\ns_barrier" ::: "memory");

    int p = 0;
    for (int t = 0; t < S_; ++t) {
        float xn2 = (t + 2 < S_) ? xrow[(size_t)(t + 2) * DST] : 0.f;

        float acc[4] = {0.f, 0.f, 0.f, 0.f};
#pragma unroll
        for (int q = 0; q < 4; ++q) {
#pragma unroll
            for (int i = 0; i < 16; i += 4) {
                float4 hv = *(const float4*)&hb[p][rh + q * 16 + i];
                acc[q] = fmaf(hv.x, w[q * 16 + i + 0], acc[q]);
                acc[q] = fmaf(hv.y, w[q * 16 + i + 1], acc[q]);
                acc[q] = fmaf(hv.z, w[q * 16 + i + 2], acc[q]);
                acc[q] = fmaf(hv.w, w[q * 16 + i + 3], acc[q]);
            }
        }
        float r = (acc[0] + acc[1]) + (acc[2] + acc[3]);
        r += __shfl_xor(r, 1, 64);           // pair-reduce across row halves
        float s = r + xv;
        // tanh(s) = 1 - 2/(exp(2s)+1), exact at +-inf
        float e = __builtin_amdgcn_exp2f(s * 2.885390081777927f); // e^{2s}
        float hn = fmaf(-2.f, __builtin_amdgcn_rcpf(e + 1.f), 1.f);

        if (!(lane & 1)) {
            hb[p ^ 1][col] = hn;
            hcol[(size_t)t * DST] = f2bf(hn);
            if (t == S_ - 1) *osp = hn;
        }
        asm volatile("s_waitcnt lgkmcnt(0)\ns_barrier" ::: "memory");
        p ^= 1;
        xv = xn1; xn1 = xn2;
    }
}

extern "C" void kernel_launch(void* const* d_in, const int* in_sizes, int n_in,
                              void* d_out, int out_size, void* d_ws, size_t ws_size,
                              hipStream_t stream) {
    const float* x    = (const float*)d_in[0];
    const float* h0   = (const float*)d_in[1];
    const float* Wi   = (const float*)d_in[2];
    const float* bias = (const float*)d_in[3];
    const float* sw   = (const float*)d_in[4];
    const float* Wo   = (const float*)d_in[5];
    float* out = (float*)d_out;

    char* ws = (char*)d_ws;
    unsigned short* xb  = (unsigned short*)ws;                     // 32MB (reused as hs bf16)
    unsigned short* wit = (unsigned short*)(ws + 33554432);        // 8MB
    unsigned short* wot = (unsigned short*)(ws + 41943040);        // 8MB
    float*          xp  = (float*)(ws + 50331648);                 // 64MB

    // 1. cast x -> bf16
    k_cast_bf16<<<8192, 256, 0, stream>>>(x, xb, (M_ * DIN) / 8);
    // 2. transpose+cast weights
    dim3 tg(32, 32);
    k_transpose_bf16<<<tg, 256, 0, stream>>>(Wi, wit, DIN, DST);
    k_transpose_bf16<<<tg, 256, 0, stream>>>(Wo, wot, DST, DOUT);
    // 3. xp = x @ Wi + b   (fp32 out)
    dim3 g1(DST / 128, M_ / 128);
    k_gemm_bt<<<g1, 256, 0, stream>>>(xb, wit, xp, bias, M_, DST, DIN, 1);
    // 4. sequential scan (writes hs bf16 over xb region + final state)
    k_scan<<<B_ * NH, 256, 0, stream>>>(xp, h0, sw, xb, out + OUT_OFF);
    // 5. out = hs @ Wo
    dim3 g2(DOUT / 128, M_ / 128);
    k_gemm_bt<<<g2, 256, 0, stream>>>(xb, wot, out, nullptr, M_, DOUT, DST, 0);
}

// Round 3
// 1025.906 us; speedup vs baseline: 1.2861x; 1.1362x over previous
//
#include <hip/hip_runtime.h>
#include <hip/hip_bf16.h>

#define B_ 4
#define S_ 2048
#define DIN 2048
#define DST 2048
#define DOUT 2048
#define NH 16
#define HH 128
#define M_ (B_ * S_)          // 8192
#define OUT_OFF ((size_t)M_ * DOUT)  // 16777216

typedef __attribute__((ext_vector_type(8))) __bf16 bf16x8;
typedef __attribute__((ext_vector_type(4))) float f32x4;
typedef __attribute__((ext_vector_type(2))) float f32x2;

__device__ __forceinline__ unsigned short f2bf(float f) {
    unsigned int u = __float_as_uint(f);
    unsigned int r = u + 0x7FFFu + ((u >> 16) & 1u);
    return (unsigned short)(r >> 16);
}

__device__ __forceinline__ void gload_lds16(const void* g, void* l) {
    __builtin_amdgcn_global_load_lds(
        (const __attribute__((address_space(1))) void*)g,
        (__attribute__((address_space(3))) void*)l, 16, 0, 0);
}

// ---------------- cast x (fp32 -> bf16), 8 elems/thread ----------------
__global__ __launch_bounds__(256) void k_cast_bf16(
    const float* __restrict__ in, unsigned short* __restrict__ out, int n8) {
    int i = blockIdx.x * 256 + threadIdx.x;
    if (i >= n8) return;
    const float4* p = ((const float4*)in) + (size_t)i * 2;
    float4 a = p[0], b = p[1];
    ushort4 r0, r1;
    r0.x = f2bf(a.x); r0.y = f2bf(a.y); r0.z = f2bf(a.z); r0.w = f2bf(a.w);
    r1.x = f2bf(b.x); r1.y = f2bf(b.y); r1.z = f2bf(b.z); r1.w = f2bf(b.w);
    ushort4* o = ((ushort4*)out) + (size_t)i * 2;
    o[0] = r0; o[1] = r1;
}

// ------------- transpose + cast: in[K][N] fp32 -> out[N][K] bf16 -------------
__global__ __launch_bounds__(256) void k_transpose_bf16(
    const float* __restrict__ in, unsigned short* __restrict__ out, int K, int N) {
    __shared__ float tile[64][65];
    int k0 = blockIdx.y * 64, n0 = blockIdx.x * 64;
    int tr  = threadIdx.x >> 4;          // 0..15
    int tc4 = (threadIdx.x & 15) * 4;    // 0..60
#pragma unroll
    for (int p = 0; p < 4; ++p) {
        int r = tr + p * 16;
        float4 v = *(const float4*)&in[(size_t)(k0 + r) * N + n0 + tc4];
        tile[r][tc4 + 0] = v.x; tile[r][tc4 + 1] = v.y;
        tile[r][tc4 + 2] = v.z; tile[r][tc4 + 3] = v.w;
    }
    __syncthreads();
#pragma unroll
    for (int p = 0; p < 4; ++p) {
        int n = tr + p * 16;
        ushort4 o;
        o.x = f2bf(tile[tc4 + 0][n]); o.y = f2bf(tile[tc4 + 1][n]);
        o.z = f2bf(tile[tc4 + 2][n]); o.w = f2bf(tile[tc4 + 3][n]);
        *(ushort4*)&out[(size_t)(n0 + n) * K + k0 + tc4] = o;
    }
}

// ---------------- bf16 GEMM: C[M][N] = A[M][K] * Bt[N][K]^T (+bias) ----------------
__global__ __launch_bounds__(256, 2) void k_gemm_bt(
    const unsigned short* __restrict__ A,
    const unsigned short* __restrict__ Bt,
    float* __restrict__ C,
    const float* __restrict__ bias,
    int M, int N, int K, int hasBias) {
    __shared__ unsigned short As[128 * 64];
    __shared__ unsigned short Bs[128 * 64];
    const int tid  = threadIdx.x;
    const int lane = tid & 63;
    const int wid  = tid >> 6;
    const int wr = wid >> 1, wc = wid & 1;
    const int row0 = blockIdx.y * 128, col0 = blockIdx.x * 128;

    f32x4 acc[4][4];
#pragma unroll
    for (int m = 0; m < 4; ++m)
#pragma unroll
        for (int n = 0; n < 4; ++n) acc[m][n] = (f32x4)(0.f);

    const char* Abase = (const char*)(A + (size_t)row0 * K);
    const char* Bbase = (const char*)(Bt + (size_t)col0 * K);

    int srow[4], skb[4];
#pragma unroll
    for (int i = 0; i < 4; ++i) {
        unsigned o = (unsigned)(i * 256 + tid) * 16u;
        unsigned l = o ^ (((o >> 7) & 7u) << 4);   // inverse-swizzled linear index
        srow[i] = (int)(l >> 7);
        skb[i]  = (int)(l & 127u);
    }

    for (int kt = 0; kt < K; kt += 64) {
#pragma unroll
        for (int i = 0; i < 4; ++i) {
            unsigned o = (unsigned)(i * 256 + tid) * 16u;
            gload_lds16(Abase + (size_t)srow[i] * (K * 2) + (size_t)kt * 2 + skb[i],
                        (char*)As + o);
            gload_lds16(Bbase + (size_t)srow[i] * (K * 2) + (size_t)kt * 2 + skb[i],
                        (char*)Bs + o);
        }
        asm volatile("s_waitcnt vmcnt(0)" ::: "memory");
        __syncthreads();
#pragma unroll
        for (int ks = 0; ks < 2; ++ks) {
            bf16x8 af[4], bfr[4];
#pragma unroll
            for (int m = 0; m < 4; ++m) {
                int row = wr * 64 + m * 16 + (lane & 15);
                unsigned o = (unsigned)(row * 128 + ks * 64 + ((lane >> 4) * 16));
                o ^= ((unsigned)(row & 7) << 4);
                af[m] = *(const bf16x8*)((const char*)As + o);
            }
#pragma unroll
            for (int n = 0; n < 4; ++n) {
                int col = wc * 64 + n * 16 + (lane & 15);
                unsigned o = (unsigned)(col * 128 + ks * 64 + ((lane >> 4) * 16));
                o ^= ((unsigned)(col & 7) << 4);
                bfr[n] = *(const bf16x8*)((const char*)Bs + o);
            }
#pragma unroll
            for (int m = 0; m < 4; ++m)
#pragma unroll
                for (int n = 0; n < 4; ++n)
                    acc[m][n] = __builtin_amdgcn_mfma_f32_16x16x32_bf16(
                        af[m], bfr[n], acc[m][n], 0, 0, 0);
        }
        __syncthreads();
    }

#pragma unroll
    for (int n = 0; n < 4; ++n) {
        int gcol = col0 + wc * 64 + n * 16 + (lane & 15);
        float bv = hasBias ? bias[gcol] : 0.f;
#pragma unroll
        for (int m = 0; m < 4; ++m) {
            int growb = row0 + wr * 64 + m * 16 + ((lane >> 4) * 4);
            float* cp = C + (size_t)growb * N + gcol;
#pragma unroll
            for (int r = 0; r < 4; ++r) cp[(size_t)r * N] = acc[m][n][r] + bv;
        }
    }
}

// ---------------- RNN scan: one WG per (batch, head) chain ----------------
// col = wave*32 + lane/2 ; row-half = (lane&1)*64.
// W half-column in 16 NAMED f32x4 (guaranteed VGPRs, no array -> no scratch).
// h in padded LDS: half0 at [0..63], half1 at [68..131] -> the two broadcast
// groups of each ds_read_b128 hit disjoint bank quads (conflict-free).
// f32x2 packed FMA (v_pk_fma_f32). One lgkmcnt-only barrier per step.
__global__ __launch_bounds__(256, 1) void k_scan(
    const float* __restrict__ xp,        // [M_][2048] fp32
    const float* __restrict__ h0,        // [B_][2048]
    const float* __restrict__ sw,        // [NH][HH][HH]
    unsigned short* __restrict__ hsb,    // [M_][2048] bf16 out
    float* __restrict__ out_state) {     // [B_][2048] fp32
    __shared__ float hb[2][136];
    const int tid  = threadIdx.x;
    const int lane = tid & 63;
    const int wv   = tid >> 6;
    const int col  = wv * 32 + (lane >> 1);
    const int rh   = (lane & 1) << 6;           // 0 or 64
    const int rbase = (lane & 1) ? 68 : 0;      // padded read base
    const int sidx = col + ((col >> 6) << 2);   // padded store index
    const int bb = blockIdx.x >> 4;
    const int nn = blockIdx.x & 15;

    const float* wbp = sw + (size_t)nn * HH * HH + (size_t)rh * HH + col;
#define LDW(k) const f32x4 w##k = { wbp[(k*4+0)*HH], wbp[(k*4+1)*HH], \
                                    wbp[(k*4+2)*HH], wbp[(k*4+3)*HH] };
    LDW(0)  LDW(1)  LDW(2)  LDW(3)  LDW(4)  LDW(5)  LDW(6)  LDW(7)
    LDW(8)  LDW(9)  LDW(10) LDW(11) LDW(12) LDW(13) LDW(14) LDW(15)
#undef LDW

    if (tid < HH) hb[0][tid + ((tid >> 6) << 2)] = h0[bb * DST + nn * HH + tid];

    const float* xrow = xp + (size_t)bb * S_ * DST + nn * HH + col;
    unsigned short* hcol = hsb + (size_t)bb * S_ * DST + nn * HH + col;
    float* osp = out_state + bb * DST + nn * HH + col;

    // 4-deep xp prefetch (named regs, manual rotate)
    float xv = xrow[0];
    float x1 = xrow[(size_t)1 * DST];
    float x2 = xrow[(size_t)2 * DST];
    float x3 = xrow[(size_t)3 * DST];

    asm volatile("s_waitcnt lgkmcnt(0)\ns_barrier" ::: "memory");

    int p = 0;
    for (int t = 0; t < S_; ++t) {
        float x4 = (t + 4 < S_) ? xrow[(size_t)(t + 4) * DST] : 0.f;

        f32x2 acca = {0.f, 0.f}, accb = {0.f, 0.f};
        f32x2 accc = {0.f, 0.f}, accd = {0.f, 0.f};
#define DOFMA(k, A, Bv) { \
        f32x4 hv = *(const f32x4*)&hb[p][rbase + (k) * 4]; \
        A  += __builtin_shufflevector(hv, hv, 0, 1) * \
              __builtin_shufflevector(w##k, w##k, 0, 1); \
        Bv += __builtin_shufflevector(hv, hv, 2, 3) * \
              __builtin_shufflevector(w##k, w##k, 2, 3); }
        DOFMA(0,  acca, accb) DOFMA(1,  accc, accd)
        DOFMA(2,  acca, accb) DOFMA(3,  accc, accd)
        DOFMA(4,  acca, accb) DOFMA(5,  accc, accd)
        DOFMA(6,  acca, accb) DOFMA(7,  accc, accd)
        DOFMA(8,  acca, accb) DOFMA(9,  accc, accd)
        DOFMA(10, acca, accb) DOFMA(11, accc, accd)
        DOFMA(12, acca, accb) DOFMA(13, accc, accd)
        DOFMA(14, acca, accb) DOFMA(15, accc, accd)
#undef DOFMA
        f32x2 acc2 = (acca + accb) + (accc + accd);
        float r = acc2.x + acc2.y;
        r += __shfl_xor(r, 1, 64);           // pair-reduce across row halves
        float s = r + xv;
        // tanh(s) = 1 - 2/(exp(2s)+1), exact at +-inf
        float e = __builtin_amdgcn_exp2f(s * 2.885390081777927f); // e^{2s}
        float hn = fmaf(-2.f, __builtin_amdgcn_rcpf(e + 1.f), 1.f);

        if (!(lane & 1)) {
            hb[p ^ 1][sidx] = hn;
            hcol[(size_t)t * DST] = f2bf(hn);
            if (t == S_ - 1) *osp = hn;
        }
        asm volatile("s_waitcnt lgkmcnt(0)\ns_barrier" ::: "memory");
        p ^= 1;
        xv = x1; x1 = x2; x2 = x3; x3 = x4;
    }
}

extern "C" void kernel_launch(void* const* d_in, const int* in_sizes, int n_in,
                              void* d_out, int out_size, void* d_ws, size_t ws_size,
                              hipStream_t stream) {
    const float* x    = (const float*)d_in[0];
    const float* h0   = (const float*)d_in[1];
    const float* Wi   = (const float*)d_in[2];
    const float* bias = (const float*)d_in[3];
    const float* sw   = (const float*)d_in[4];
    const float* Wo   = (const float*)d_in[5];
    float* out = (float*)d_out;

    char* ws = (char*)d_ws;
    unsigned short* xb  = (unsigned short*)ws;                     // 32MB (reused as hs bf16)
    unsigned short* wit = (unsigned short*)(ws + 33554432);        // 8MB
    unsigned short* wot = (unsigned short*)(ws + 41943040);        // 8MB
    float*          xp  = (float*)(ws + 50331648);                 // 64MB

    // 1. cast x -> bf16
    k_cast_bf16<<<8192, 256, 0, stream>>>(x, xb, (M_ * DIN) / 8);
    // 2. transpose+cast weights
    dim3 tg(32, 32);
    k_transpose_bf16<<<tg, 256, 0, stream>>>(Wi, wit, DIN, DST);
    k_transpose_bf16<<<tg, 256, 0, stream>>>(Wo, wot, DST, DOUT);
    // 3. xp = x @ Wi + b   (fp32 out)
    dim3 g1(DST / 128, M_ / 128);
    k_gemm_bt<<<g1, 256, 0, stream>>>(xb, wit, xp, bias, M_, DST, DIN, 1);
    // 4. sequential scan (writes hs bf16 over xb region + final state)
    k_scan<<<B_ * NH, 256, 0, stream>>>(xp, h0, sw, xb, out + OUT_OFF);
    // 5. out = hs @ Wo
    dim3 g2(DOUT / 128, M_ / 128);
    k_gemm_bt<<<g2, 256, 0, stream>>>(xb, wot, out, nullptr, M_, DOUT, DST, 0);
}

// Round 4
// 1010.884 us; speedup vs baseline: 1.3052x; 1.0149x over previous
//
#include <hip/hip_runtime.h>
#include <hip/hip_bf16.h>

#define B_ 4
#define S_ 2048
#define DIN 2048
#define DST 2048
#define DOUT 2048
#define NH 16
#define HH 128
#define M_ (B_ * S_)          // 8192
#define OUT_OFF ((size_t)M_ * DOUT)  // 16777216

typedef __attribute__((ext_vector_type(8))) __bf16 bf16x8;
typedef __attribute__((ext_vector_type(4))) float f32x4;
typedef __attribute__((ext_vector_type(2))) float f32x2;

__device__ __forceinline__ unsigned short f2bf(float f) {
    unsigned int u = __float_as_uint(f);
    unsigned int r = u + 0x7FFFu + ((u >> 16) & 1u);
    return (unsigned short)(r >> 16);
}

__device__ __forceinline__ void gload_lds16(const void* g, void* l) {
    __builtin_amdgcn_global_load_lds(
        (const __attribute__((address_space(1))) void*)g,
        (__attribute__((address_space(3))) void*)l, 16, 0, 0);
}

// ---------------- cast x (fp32 -> bf16), 8 elems/thread ----------------
__global__ __launch_bounds__(256) void k_cast_bf16(
    const float* __restrict__ in, unsigned short* __restrict__ out, int n8) {
    int i = blockIdx.x * 256 + threadIdx.x;
    if (i >= n8) return;
    const float4* p = ((const float4*)in) + (size_t)i * 2;
    float4 a = p[0], b = p[1];
    ushort4 r0, r1;
    r0.x = f2bf(a.x); r0.y = f2bf(a.y); r0.z = f2bf(a.z); r0.w = f2bf(a.w);
    r1.x = f2bf(b.x); r1.y = f2bf(b.y); r1.z = f2bf(b.z); r1.w = f2bf(b.w);
    ushort4* o = ((ushort4*)out) + (size_t)i * 2;
    o[0] = r0; o[1] = r1;
}

// ------------- transpose + cast: in[K][N] fp32 -> out[N][K] bf16 -------------
__global__ __launch_bounds__(256) void k_transpose_bf16(
    const float* __restrict__ in, unsigned short* __restrict__ out, int K, int N) {
    __shared__ float tile[64][65];
    int k0 = blockIdx.y * 64, n0 = blockIdx.x * 64;
    int tr  = threadIdx.x >> 4;          // 0..15
    int tc4 = (threadIdx.x & 15) * 4;    // 0..60
#pragma unroll
    for (int p = 0; p < 4; ++p) {
        int r = tr + p * 16;
        float4 v = *(const float4*)&in[(size_t)(k0 + r) * N + n0 + tc4];
        tile[r][tc4 + 0] = v.x; tile[r][tc4 + 1] = v.y;
        tile[r][tc4 + 2] = v.z; tile[r][tc4 + 3] = v.w;
    }
    __syncthreads();
#pragma unroll
    for (int p = 0; p < 4; ++p) {
        int n = tr + p * 16;
        ushort4 o;
        o.x = f2bf(tile[tc4 + 0][n]); o.y = f2bf(tile[tc4 + 1][n]);
        o.z = f2bf(tile[tc4 + 2][n]); o.w = f2bf(tile[tc4 + 3][n]);
        *(ushort4*)&out[(size_t)(n0 + n) * K + k0 + tc4] = o;
    }
}

// ---------------- bf16 GEMM: C[M][N] = A[M][K] * Bt[N][K]^T (+bias) ----------------
__global__ __launch_bounds__(256, 2) void k_gemm_bt(
    const unsigned short* __restrict__ A,
    const unsigned short* __restrict__ Bt,
    float* __restrict__ C,
    const float* __restrict__ bias,
    int M, int N, int K, int hasBias) {
    __shared__ unsigned short As[128 * 64];
    __shared__ unsigned short Bs[128 * 64];
    const int tid  = threadIdx.x;
    const int lane = tid & 63;
    const int wid  = tid >> 6;
    const int wr = wid >> 1, wc = wid & 1;
    const int row0 = blockIdx.y * 128, col0 = blockIdx.x * 128;

    f32x4 acc[4][4];
#pragma unroll
    for (int m = 0; m < 4; ++m)
#pragma unroll
        for (int n = 0; n < 4; ++n) acc[m][n] = (f32x4)(0.f);

    const char* Abase = (const char*)(A + (size_t)row0 * K);
    const char* Bbase = (const char*)(Bt + (size_t)col0 * K);

    int srow[4], skb[4];
#pragma unroll
    for (int i = 0; i < 4; ++i) {
        unsigned o = (unsigned)(i * 256 + tid) * 16u;
        unsigned l = o ^ (((o >> 7) & 7u) << 4);   // inverse-swizzled linear index
        srow[i] = (int)(l >> 7);
        skb[i]  = (int)(l & 127u);
    }

    for (int kt = 0; kt < K; kt += 64) {
#pragma unroll
        for (int i = 0; i < 4; ++i) {
            unsigned o = (unsigned)(i * 256 + tid) * 16u;
            gload_lds16(Abase + (size_t)srow[i] * (K * 2) + (size_t)kt * 2 + skb[i],
                        (char*)As + o);
            gload_lds16(Bbase + (size_t)srow[i] * (K * 2) + (size_t)kt * 2 + skb[i],
                        (char*)Bs + o);
        }
        asm volatile("s_waitcnt vmcnt(0)" ::: "memory");
        __syncthreads();
#pragma unroll
        for (int ks = 0; ks < 2; ++ks) {
            bf16x8 af[4], bfr[4];
#pragma unroll
            for (int m = 0; m < 4; ++m) {
                int row = wr * 64 + m * 16 + (lane & 15);
                unsigned o = (unsigned)(row * 128 + ks * 64 + ((lane >> 4) * 16));
                o ^= ((unsigned)(row & 7) << 4);
                af[m] = *(const bf16x8*)((const char*)As + o);
            }
#pragma unroll
            for (int n = 0; n < 4; ++n) {
                int col = wc * 64 + n * 16 + (lane & 15);
                unsigned o = (unsigned)(col * 128 + ks * 64 + ((lane >> 4) * 16));
                o ^= ((unsigned)(col & 7) << 4);
                bfr[n] = *(const bf16x8*)((const char*)Bs + o);
            }
#pragma unroll
            for (int m = 0; m < 4; ++m)
#pragma unroll
                for (int n = 0; n < 4; ++n)
                    acc[m][n] = __builtin_amdgcn_mfma_f32_16x16x32_bf16(
                        af[m], bfr[n], acc[m][n], 0, 0, 0);
        }
        __syncthreads();
    }

#pragma unroll
    for (int n = 0; n < 4; ++n) {
        int gcol = col0 + wc * 64 + n * 16 + (lane & 15);
        float bv = hasBias ? bias[gcol] : 0.f;
#pragma unroll
        for (int m = 0; m < 4; ++m) {
            int growb = row0 + wr * 64 + m * 16 + ((lane >> 4) * 4);
            float* cp = C + (size_t)growb * N + gcol;
#pragma unroll
            for (int r = 0; r < 4; ++r) cp[(size_t)r * N] = acc[m][n][r] + bv;
        }
    }
}

// ---------------- RNN scan: one WG per (batch, head) chain ----------------
// col = wave*32 + lane/2 ; row-half = (lane&1)*64.
// W half-column in 16 NAMED f32x4. amdgpu_waves_per_eu(1,1) pins the
// occupancy target to 1 wave/EU (we only ever run 1 block/CU) so the
// allocator's VGPR budget is 512, not 64 -> weights stay register-resident.
// h in padded LDS (conflict-free); f32x2 packed FMA; one lgkmcnt-only
// barrier per step (global stores + xp prefetch never drained).
__global__ __attribute__((amdgpu_flat_work_group_size(256, 256),
                          amdgpu_waves_per_eu(1, 1))) void k_scan(
    const float* __restrict__ xp,        // [M_][2048] fp32
    const float* __restrict__ h0,        // [B_][2048]
    const float* __restrict__ sw,        // [NH][HH][HH]
    unsigned short* __restrict__ hsb,    // [M_][2048] bf16 out
    float* __restrict__ out_state) {     // [B_][2048] fp32
    __shared__ float hb[2][136];
    const int tid  = threadIdx.x;
    const int lane = tid & 63;
    const int wv   = tid >> 6;
    const int col  = wv * 32 + (lane >> 1);
    const int rh   = (lane & 1) << 6;           // 0 or 64
    const int rbase = (lane & 1) ? 68 : 0;      // padded read base
    const int sidx = col + ((col >> 6) << 2);   // padded store index
    const int bb = blockIdx.x >> 4;
    const int nn = blockIdx.x & 15;

    const float* wbp = sw + (size_t)nn * HH * HH + (size_t)rh * HH + col;
#define LDW(k) const f32x4 w##k = { wbp[(k*4+0)*HH], wbp[(k*4+1)*HH], \
                                    wbp[(k*4+2)*HH], wbp[(k*4+3)*HH] };
    LDW(0)  LDW(1)  LDW(2)  LDW(3)  LDW(4)  LDW(5)  LDW(6)  LDW(7)
    LDW(8)  LDW(9)  LDW(10) LDW(11) LDW(12) LDW(13) LDW(14) LDW(15)
#undef LDW

    if (tid < HH) hb[0][tid + ((tid >> 6) << 2)] = h0[bb * DST + nn * HH + tid];

    const float* xrow = xp + (size_t)bb * S_ * DST + nn * HH + col;
    unsigned short* hcol = hsb + (size_t)bb * S_ * DST + nn * HH + col;
    float* osp = out_state + bb * DST + nn * HH + col;

    // 4-deep xp prefetch (named regs, manual rotate)
    float xv = xrow[0];
    float x1 = xrow[(size_t)1 * DST];
    float x2 = xrow[(size_t)2 * DST];
    float x3 = xrow[(size_t)3 * DST];

    asm volatile("s_waitcnt lgkmcnt(0)\ns_barrier" ::: "memory");

    int p = 0;
    for (int t = 0; t < S_; ++t) {
        float x4 = (t + 4 < S_) ? xrow[(size_t)(t + 4) * DST] : 0.f;

        f32x2 acca = {0.f, 0.f}, accb = {0.f, 0.f};
        f32x2 accc = {0.f, 0.f}, accd = {0.f, 0.f};
#define DOFMA(k, A, Bv) { \
        f32x4 hv = *(const f32x4*)&hb[p][rbase + (k) * 4]; \
        A  += __builtin_shufflevector(hv, hv, 0, 1) * \
              __builtin_shufflevector(w##k, w##k, 0, 1); \
        Bv += __builtin_shufflevector(hv, hv, 2, 3) * \
              __builtin_shufflevector(w##k, w##k, 2, 3); }
        DOFMA(0,  acca, accb) DOFMA(1,  accc, accd)
        DOFMA(2,  acca, accb) DOFMA(3,  accc, accd)
        DOFMA(4,  acca, accb) DOFMA(5,  accc, accd)
        DOFMA(6,  acca, accb) DOFMA(7,  accc, accd)
        DOFMA(8,  acca, accb) DOFMA(9,  accc, accd)
        DOFMA(10, acca, accb) DOFMA(11, accc, accd)
        DOFMA(12, acca, accb) DOFMA(13, accc, accd)
        DOFMA(14, acca, accb) DOFMA(15, accc, accd)
#undef DOFMA
        f32x2 acc2 = (acca + accb) + (accc + accd);
        float r = acc2.x + acc2.y;
        r += __shfl_xor(r, 1, 64);           // pair-reduce across row halves
        float s = r + xv;
        // tanh(s) = 1 - 2/(exp(2s)+1), exact at +-inf
        float e = __builtin_amdgcn_exp2f(s * 2.885390081777927f); // e^{2s}
        float hn = fmaf(-2.f, __builtin_amdgcn_rcpf(e + 1.f), 1.f);

        if (!(lane & 1)) {
            hb[p ^ 1][sidx] = hn;
            hcol[(size_t)t * DST] = f2bf(hn);
            if (t == S_ - 1) *osp = hn;
        }
        asm volatile("s_waitcnt lgkmcnt(0)\ns_barrier" ::: "memory");
        p ^= 1;
        xv = x1; x1 = x2; x2 = x3; x3 = x4;
    }
}

extern "C" void kernel_launch(void* const* d_in, const int* in_sizes, int n_in,
                              void* d_out, int out_size, void* d_ws, size_t ws_size,
                              hipStream_t stream) {
    const float* x    = (const float*)d_in[0];
    const float* h0   = (const float*)d_in[1];
    const float* Wi   = (const float*)d_in[2];
    const float* bias = (const float*)d_in[3];
    const float* sw   = (const float*)d_in[4];
    const float* Wo   = (const float*)d_in[5];
    float* out = (float*)d_out;

    char* ws = (char*)d_ws;
    unsigned short* xb  = (unsigned short*)ws;                     // 32MB (reused as hs bf16)
    unsigned short* wit = (unsigned short*)(ws + 33554432);        // 8MB
    unsigned short* wot = (unsigned short*)(ws + 41943040);        // 8MB
    float*          xp  = (float*)(ws + 50331648);                 // 64MB

    // 1. cast x -> bf16
    k_cast_bf16<<<8192, 256, 0, stream>>>(x, xb, (M_ * DIN) / 8);
    // 2. transpose+cast weights
    dim3 tg(32, 32);
    k_transpose_bf16<<<tg, 256, 0, stream>>>(Wi, wit, DIN, DST);
    k_transpose_bf16<<<tg, 256, 0, stream>>>(Wo, wot, DST, DOUT);
    // 3. xp = x @ Wi + b   (fp32 out)
    dim3 g1(DST / 128, M_ / 128);
    k_gemm_bt<<<g1, 256, 0, stream>>>(xb, wit, xp, bias, M_, DST, DIN, 1);
    // 4. sequential scan (writes hs bf16 over xb region + final state)
    k_scan<<<B_ * NH, 256, 0, stream>>>(xp, h0, sw, xb, out + OUT_OFF);
    // 5. out = hs @ Wo
    dim3 g2(DOUT / 128, M_ / 128);
    k_gemm_bt<<<g2, 256, 0, stream>>>(xb, wot, out, nullptr, M_, DOUT, DST, 0);
}

// Round 5
// 863.615 us; speedup vs baseline: 1.5278x; 1.1705x over previous
//
#include <hip/hip_runtime.h>
#include <hip/hip_bf16.h>

#define B_ 4
#define S_ 2048
#define DIN 2048
#define DST 2048
#define DOUT 2048
#define NH 16
#define HH 128
#define M_ (B_ * S_)          // 8192
#define OUT_OFF ((size_t)M_ * DOUT)  // 16777216

typedef __attribute__((ext_vector_type(8))) __bf16 bf16x8;
typedef __attribute__((ext_vector_type(4))) float f32x4;
typedef __attribute__((ext_vector_type(2))) _Float16 f16x2;

__device__ __forceinline__ unsigned short f2bf(float f) {
    unsigned int u = __float_as_uint(f);
    unsigned int r = u + 0x7FFFu + ((u >> 16) & 1u);
    return (unsigned short)(r >> 16);
}

__device__ __forceinline__ float fdot2(f16x2 a, f16x2 b, float c) {
#if __has_builtin(__builtin_amdgcn_fdot2)
    return __builtin_amdgcn_fdot2(a, b, c, false);
#else
    return fmaf((float)a.x, (float)b.x, fmaf((float)a.y, (float)b.y, c));
#endif
}

// quad_perm DPP: xor1 = 0xB1, xor2 = 0x4E (register-only cross-lane)
#define DPP_PULL(v, ctrl) __builtin_bit_cast(float, \
    __builtin_amdgcn_mov_dpp(__builtin_bit_cast(int, (v)), (ctrl), 0xf, 0xf, true))

__device__ __forceinline__ void gload_lds16(const void* g, void* l) {
    __builtin_amdgcn_global_load_lds(
        (const __attribute__((address_space(1))) void*)g,
        (__attribute__((address_space(3))) void*)l, 16, 0, 0);
}

// ---------------- cast x (fp32 -> bf16), 8 elems/thread ----------------
__global__ __launch_bounds__(256) void k_cast_bf16(
    const float* __restrict__ in, unsigned short* __restrict__ out, int n8) {
    int i = blockIdx.x * 256 + threadIdx.x;
    if (i >= n8) return;
    const float4* p = ((const float4*)in) + (size_t)i * 2;
    float4 a = p[0], b = p[1];
    ushort4 r0, r1;
    r0.x = f2bf(a.x); r0.y = f2bf(a.y); r0.z = f2bf(a.z); r0.w = f2bf(a.w);
    r1.x = f2bf(b.x); r1.y = f2bf(b.y); r1.z = f2bf(b.z); r1.w = f2bf(b.w);
    ushort4* o = ((ushort4*)out) + (size_t)i * 2;
    o[0] = r0; o[1] = r1;
}

// ------------- transpose + cast: in[K][N] fp32 -> out[N][K] bf16 -------------
__global__ __launch_bounds__(256) void k_transpose_bf16(
    const float* __restrict__ in, unsigned short* __restrict__ out, int K, int N) {
    __shared__ float tile[64][65];
    int k0 = blockIdx.y * 64, n0 = blockIdx.x * 64;
    int tr  = threadIdx.x >> 4;          // 0..15
    int tc4 = (threadIdx.x & 15) * 4;    // 0..60
#pragma unroll
    for (int p = 0; p < 4; ++p) {
        int r = tr + p * 16;
        float4 v = *(const float4*)&in[(size_t)(k0 + r) * N + n0 + tc4];
        tile[r][tc4 + 0] = v.x; tile[r][tc4 + 1] = v.y;
        tile[r][tc4 + 2] = v.z; tile[r][tc4 + 3] = v.w;
    }
    __syncthreads();
#pragma unroll
    for (int p = 0; p < 4; ++p) {
        int n = tr + p * 16;
        ushort4 o;
        o.x = f2bf(tile[tc4 + 0][n]); o.y = f2bf(tile[tc4 + 1][n]);
        o.z = f2bf(tile[tc4 + 2][n]); o.w = f2bf(tile[tc4 + 3][n]);
        *(ushort4*)&out[(size_t)(n0 + n) * K + k0 + tc4] = o;
    }
}

// ---------------- bf16 GEMM: C[M][N] = A[M][K] * Bt[N][K]^T (+bias) ----------------
__global__ __launch_bounds__(256, 2) void k_gemm_bt(
    const unsigned short* __restrict__ A,
    const unsigned short* __restrict__ Bt,
    float* __restrict__ C,
    const float* __restrict__ bias,
    int M, int N, int K, int hasBias) {
    __shared__ unsigned short As[128 * 64];
    __shared__ unsigned short Bs[128 * 64];
    const int tid  = threadIdx.x;
    const int lane = tid & 63;
    const int wid  = tid >> 6;
    const int wr = wid >> 1, wc = wid & 1;
    const int row0 = blockIdx.y * 128, col0 = blockIdx.x * 128;

    f32x4 acc[4][4];
#pragma unroll
    for (int m = 0; m < 4; ++m)
#pragma unroll
        for (int n = 0; n < 4; ++n) acc[m][n] = (f32x4)(0.f);

    const char* Abase = (const char*)(A + (size_t)row0 * K);
    const char* Bbase = (const char*)(Bt + (size_t)col0 * K);

    int srow[4], skb[4];
#pragma unroll
    for (int i = 0; i < 4; ++i) {
        unsigned o = (unsigned)(i * 256 + tid) * 16u;
        unsigned l = o ^ (((o >> 7) & 7u) << 4);   // inverse-swizzled linear index
        srow[i] = (int)(l >> 7);
        skb[i]  = (int)(l & 127u);
    }

    for (int kt = 0; kt < K; kt += 64) {
#pragma unroll
        for (int i = 0; i < 4; ++i) {
            unsigned o = (unsigned)(i * 256 + tid) * 16u;
            gload_lds16(Abase + (size_t)srow[i] * (K * 2) + (size_t)kt * 2 + skb[i],
                        (char*)As + o);
            gload_lds16(Bbase + (size_t)srow[i] * (K * 2) + (size_t)kt * 2 + skb[i],
                        (char*)Bs + o);
        }
        asm volatile("s_waitcnt vmcnt(0)" ::: "memory");
        __syncthreads();
#pragma unroll
        for (int ks = 0; ks < 2; ++ks) {
            bf16x8 af[4], bfr[4];
#pragma unroll
            for (int m = 0; m < 4; ++m) {
                int row = wr * 64 + m * 16 + (lane & 15);
                unsigned o = (unsigned)(row * 128 + ks * 64 + ((lane >> 4) * 16));
                o ^= ((unsigned)(row & 7) << 4);
                af[m] = *(const bf16x8*)((const char*)As + o);
            }
#pragma unroll
            for (int n = 0; n < 4; ++n) {
                int col = wc * 64 + n * 16 + (lane & 15);
                unsigned o = (unsigned)(col * 128 + ks * 64 + ((lane >> 4) * 16));
                o ^= ((unsigned)(col & 7) << 4);
                bfr[n] = *(const bf16x8*)((const char*)Bs + o);
            }
#pragma unroll
            for (int m = 0; m < 4; ++m)
#pragma unroll
                for (int n = 0; n < 4; ++n)
                    acc[m][n] = __builtin_amdgcn_mfma_f32_16x16x32_bf16(
                        af[m], bfr[n], acc[m][n], 0, 0, 0);
        }
        __syncthreads();
    }

#pragma unroll
    for (int n = 0; n < 4; ++n) {
        int gcol = col0 + wc * 64 + n * 16 + (lane & 15);
        float bv = hasBias ? bias[gcol] : 0.f;
#pragma unroll
        for (int m = 0; m < 4; ++m) {
            int growb = row0 + wr * 64 + m * 16 + ((lane >> 4) * 4);
            float* cp = C + (size_t)growb * N + gcol;
#pragma unroll
            for (int r = 0; r < 4; ++r) cp[(size_t)r * N] = acc[m][n][r] + bv;
        }
    }
}

// ---------------- RNN scan v5: fp16 h/W + dot2, 32x2 tiling ----------------
// One WG per (b,n). 4-lane group owns 2 cols; lane q=l&3 owns rows q*32..+31.
// h in LDS as 64 dwords of f16x2 -> each lane reads 64 B/step (4x b128):
// 16 KB/step LDS traffic (was 64 KB). Weights: 32 named f16x2 VGPRs.
// Reduce across the 4-lane group with quad_perm DPP adds (no LDS, no shfl).
// One lgkmcnt-only barrier per step.
__global__ __attribute__((amdgpu_flat_work_group_size(256, 256),
                          amdgpu_waves_per_eu(1, 1))) void k_scan(
    const float* __restrict__ xp,        // [M_][2048] fp32
    const float* __restrict__ h0,        // [B_][2048]
    const float* __restrict__ sw,        // [NH][HH][HH]
    unsigned short* __restrict__ hsb,    // [M_][2048] bf16 out
    float* __restrict__ out_state) {     // [B_][2048] fp32
    __shared__ __align__(16) unsigned hb[2][64];
    const int tid  = threadIdx.x;
    const int lane = tid & 63;
    const int wv   = tid >> 6;
    const int G    = wv * 16 + (lane >> 2);   // col-pair id 0..63
    const int q    = lane & 3;                // row-block id
    const int col0 = G * 2;
    const int bb = blockIdx.x >> 4;
    const int nn = blockIdx.x & 15;

    // W[q*32 + 2j + {0,1}][col0 + {0,1}] -> 32 named f16x2 regs
    const float* wbp = sw + (size_t)nn * HH * HH + (size_t)(q * 32) * HH + col0;
#define MKW(j) f16x2 wA##j, wB##j; { const float* pw = wbp + (size_t)(2 * (j)) * HH; \
        wA##j = f16x2{(_Float16)pw[0], (_Float16)pw[HH]};                            \
        wB##j = f16x2{(_Float16)pw[1], (_Float16)pw[HH + 1]}; }
    MKW(0)  MKW(1)  MKW(2)  MKW(3)  MKW(4)  MKW(5)  MKW(6)  MKW(7)
    MKW(8)  MKW(9)  MKW(10) MKW(11) MKW(12) MKW(13) MKW(14) MKW(15)
#undef MKW

    if (tid < 64) {
        float2 h2 = *(const float2*)(h0 + bb * DST + nn * HH + 2 * tid);
        unsigned lo = __builtin_bit_cast(unsigned short, (_Float16)h2.x);
        unsigned hi = __builtin_bit_cast(unsigned short, (_Float16)h2.y);
        hb[0][tid] = lo | (hi << 16);
    }

    const float2* xrow2 = (const float2*)(xp + (size_t)bb * S_ * DST + nn * HH) + G;
    unsigned* hcol32 = (unsigned*)(hsb + (size_t)bb * S_ * DST + nn * HH) + G;
    float* osp = out_state + bb * DST + nn * HH + col0;

    // 4-deep xp prefetch (float2: both cols)
    float2 xq0 = xrow2[0];
    float2 xq1 = xrow2[(size_t)1 * (DST / 2)];
    float2 xq2 = xrow2[(size_t)2 * (DST / 2)];
    float2 xq3 = xrow2[(size_t)3 * (DST / 2)];

    asm volatile("s_waitcnt lgkmcnt(0)\ns_barrier" ::: "memory");

    int p = 0;
    for (int t = 0; t < S_; ++t) {
        int tp = (t + 4 < S_) ? t + 4 : S_ - 1;
        float2 xq4 = xrow2[(size_t)tp * (DST / 2)];

        const uint4* hp = (const uint4*)&hb[p][q * 16];
        uint4 Ra = hp[0], Rb = hp[1], Rc = hp[2], Rd = hp[3];

        float a0e = 0.f, a0o = 0.f, a1e = 0.f, a1o = 0.f;
#define D2(u, j, s) { f16x2 hj = __builtin_bit_cast(f16x2, (unsigned)(u)); \
        a0##s = fdot2(hj, wA##j, a0##s); a1##s = fdot2(hj, wB##j, a1##s); }
        D2(Ra.x, 0,  e) D2(Ra.y, 1,  o) D2(Ra.z, 2,  e) D2(Ra.w, 3,  o)
        D2(Rb.x, 4,  e) D2(Rb.y, 5,  o) D2(Rb.z, 6,  e) D2(Rb.w, 7,  o)
        D2(Rc.x, 8,  e) D2(Rc.y, 9,  o) D2(Rc.z, 10, e) D2(Rc.w, 11, o)
        D2(Rd.x, 12, e) D2(Rd.y, 13, o) D2(Rd.z, 14, e) D2(Rd.w, 15, o)
#undef D2
        float r0 = a0e + a0o;
        float r1 = a1e + a1o;
        // reduce across the 4-lane group: xor1 then xor2 (quad_perm DPP)
        r0 += DPP_PULL(r0, 0xB1); r0 += DPP_PULL(r0, 0x4E);
        r1 += DPP_PULL(r1, 0xB1); r1 += DPP_PULL(r1, 0x4E);

        float s0 = r0 + xq0.x;
        float s1 = r1 + xq0.y;
        float ssel = (lane & 1) ? s1 : s0;
        // tanh(s) = 1 - 2/(exp(2s)+1), exact at +-inf
        float e = __builtin_amdgcn_exp2f(ssel * 2.885390081777927f);
        float th = fmaf(-2.f, __builtin_amdgcn_rcpf(e + 1.f), 1.f);
        float uo = DPP_PULL(th, 0xB1);   // partner's tanh: q=0 gets t(s1)

        if (q == 0) {
            unsigned lo16 = __builtin_bit_cast(unsigned short, (_Float16)th);
            unsigned hi16 = __builtin_bit_cast(unsigned short, (_Float16)uo);
            hb[p ^ 1][G] = lo16 | (hi16 << 16);
            hcol32[(size_t)t * (DST / 2)] = (unsigned)f2bf(th) | ((unsigned)f2bf(uo) << 16);
            if (t == S_ - 1) { osp[0] = th; osp[1] = uo; }
        }
        asm volatile("s_waitcnt lgkmcnt(0)\ns_barrier" ::: "memory");
        p ^= 1;
        xq0 = xq1; xq1 = xq2; xq2 = xq3; xq3 = xq4;
    }
}

extern "C" void kernel_launch(void* const* d_in, const int* in_sizes, int n_in,
                              void* d_out, int out_size, void* d_ws, size_t ws_size,
                              hipStream_t stream) {
    const float* x    = (const float*)d_in[0];
    const float* h0   = (const float*)d_in[1];
    const float* Wi   = (const float*)d_in[2];
    const float* bias = (const float*)d_in[3];
    const float* sw   = (const float*)d_in[4];
    const float* Wo   = (const float*)d_in[5];
    float* out = (float*)d_out;

    char* ws = (char*)d_ws;
    unsigned short* xb  = (unsigned short*)ws;                     // 32MB (reused as hs bf16)
    unsigned short* wit = (unsigned short*)(ws + 33554432);        // 8MB
    unsigned short* wot = (unsigned short*)(ws + 41943040);        // 8MB
    float*          xp  = (float*)(ws + 50331648);                 // 64MB

    // 1. cast x -> bf16
    k_cast_bf16<<<8192, 256, 0, stream>>>(x, xb, (M_ * DIN) / 8);
    // 2. transpose+cast weights
    dim3 tg(32, 32);
    k_transpose_bf16<<<tg, 256, 0, stream>>>(Wi, wit, DIN, DST);
    k_transpose_bf16<<<tg, 256, 0, stream>>>(Wo, wot, DST, DOUT);
    // 3. xp = x @ Wi + b   (fp32 out)
    dim3 g1(DST / 128, M_ / 128);
    k_gemm_bt<<<g1, 256, 0, stream>>>(xb, wit, xp, bias, M_, DST, DIN, 1);
    // 4. sequential scan (writes hs bf16 over xb region + final state)
    k_scan<<<B_ * NH, 256, 0, stream>>>(xp, h0, sw, xb, out + OUT_OFF);
    // 5. out = hs @ Wo
    dim3 g2(DOUT / 128, M_ / 128);
    k_gemm_bt<<<g2, 256, 0, stream>>>(xb, wot, out, nullptr, M_, DOUT, DST, 0);
}